// Round 6
// baseline (470.605 us; speedup 1.0000x reference)
//
#include <hip/hip_runtime.h>
#include <math.h>

// GNNMLP via f16 MFMA, TRANSPOSED-ACTIVATION form. G=131072 groups x 6 agents.
// ROUND-6 RESTRUCTURE: rounds 0-5 were dominated by C->LDS->A transpose
//   round-trips (17/wave, each ds_write+lgkmcnt+ds_read+cvt serialized; waves
//   92% stalled; occupancy 20->42% changed nothing). Key identity: for
//   mfma_f32_16x16x16_f16, D layout (col=lane&15,row=quad*4+reg) == operand
//   layout (n=lane&15,k=quad*4+j). So D (cvt'd to f16 per-reg) IS a valid
//   B-operand for the next layer with NO transpose. Compute every layer
//   transposed: D = W^T (A, from prep image) x X^T (B, prev D). Activations
//   live as [feature][group], group-in-lane. ZERO data LDS; all layer
//   chaining in registers.
// prep_weights: img = 12 matrices of W^T A-frags (mt,kt tiles, 8 B/lane/frag,
//   (mt*4+kt)*256 + lane*4 packing) + head A-frags (2 ty sets, D-rows 0..11 =
//   12 output slots, zero-padded, C-chained over ty).
// Pooling: max/mean over agents is elementwise on D-frags (any fixed layout).
// OCCUPANCY (R1/R2 lesson): LDS pad 71680 B caps 2 blocks/CU = 4 waves/EU so
//   the allocator targets <=128 VGPR without spill-squeeze; launch_bounds(512,2).
// Weights loaded per-use behind asm opacity barriers (R5-proven) so the
//   allocator streams them from L1 instead of hoisting 64+ VGPRs.
// Layouts (m89/m120-verified family, K=16 variant):
//   A[m][k]: m=lane&15, k=(lane>>4)*4+j   B[k][n]: n=lane&15, k=(lane>>4)*4+j
//   C/D:     col=lane&15, row=(lane>>4)*4+reg

typedef _Float16 f16;
typedef __fp16   fp16x2_t __attribute__((ext_vector_type(2)));
typedef _Float16 half4_t  __attribute__((ext_vector_type(4)));
typedef float    float4_t __attribute__((ext_vector_type(4)));

#define NW 8            // waves per block
#define LDS_PAD_F 17920 // 71680 B: floor(163840/71680) = 2 blocks/CU cap

#define MFMA16(A,B,C) __builtin_amdgcn_mfma_f32_16x16x16f16((A),(B),(C),0,0,0)

__device__ __forceinline__ float fast_tanh(float x) {
    float e = __expf(2.0f * x);
    return 1.0f - 2.0f / (e + 1.0f);
}

__device__ __forceinline__ float4_t max4(float4_t a, float4_t b) {
    float4_t r;
    r[0] = fmaxf(a[0], b[0]); r[1] = fmaxf(a[1], b[1]);
    r[2] = fmaxf(a[2], b[2]); r[3] = fmaxf(a[3], b[3]);
    return r;
}

__device__ __forceinline__ float4_t bcast4(float v) {
    float4_t r; r[0] = v; r[1] = v; r[2] = v; r[3] = v; return r;
}

// f32x4 -> f16x4 via 2 packed cvt
__device__ __forceinline__ half4_t cvt4(float4_t v) {
    fp16x2_t p0 = __builtin_amdgcn_cvt_pkrtz(v[0], v[1]);
    fp16x2_t p1 = __builtin_amdgcn_cvt_pkrtz(v[2], v[3]);
    half4_t r;
    r[0] = (f16)p0[0]; r[1] = (f16)p0[1]; r[2] = (f16)p1[0]; r[3] = (f16)p1[1];
    return r;
}

// ---------------- prep: W^T A-fragment image in d_ws ----------------
// matrix m: frag (mt,kt): img[m*4096 + (mt*4+kt)*256 + lane*4 + j]
//   = W^T[mt*16+(lane&15)][kt*16+(lane>>4)*4+j] = W[k][n] (src row-major in->out)
__global__ void prep_weights(const float* __restrict__ Wp1, const float* __restrict__ Ws1,
                             const float* __restrict__ Wn1, const float* __restrict__ Wp2,
                             const float* __restrict__ Ws2, const float* __restrict__ Wn2,
                             const float* __restrict__ MW1, const float* __restrict__ MW2,
                             const float* __restrict__ MW3, const float* __restrict__ MW4,
                             f16* __restrict__ img)
{
    const int m = blockIdx.x;
    const int tid = threadIdx.x;
    if (m < 12) {
        const float* src;
        switch (m) {
            case 0: src = Wp1; break;  case 1: src = Ws1; break;
            case 2: src = Wn1; break;  case 3: src = Wp2; break;
            case 4: src = Ws2; break;  case 5: src = Wn2; break;
            case 6: src = MW1; break;  case 7: src = MW2; break;
            case 8: src = MW3; break;  case 9: src = MW1 + 4096; break;
            case 10: src = MW2 + 4096; break; default: src = MW3 + 4096; break;
        }
        for (int e = tid; e < 4096; e += 256) {
            const int mt = e >> 10, o = e & 1023;
            const int kt = o >> 8, lane = (o >> 2) & 63, j = e & 3;
            const int k = kt * 16 + (lane >> 4) * 4 + j;
            const int n = mt * 16 + (lane & 15);
            img[m * 4096 + e] = (f16)src[k * 64 + n];
        }
    } else {
        // head: ty sets of A-frags; D rows (m) 0..9 = ty0 agent-slots (MW4[0],
        // out-dim m&1), rows 10,11 = ty1; rest zero. C-chained over ty.
        for (int e = tid; e < 2048; e += 256) {
            const int ty = e >> 10, o = e & 1023;
            const int kt = o >> 8, lane = (o >> 2) & 63, j = e & 3;
            const int k = kt * 16 + (lane >> 4) * 4 + j;
            const int mm = lane & 15;
            float v = 0.f;
            if (ty == 0) { if (mm < 10) v = MW4[k * 2 + (mm & 1)]; }
            else         { if (mm == 10 || mm == 11) v = MW4[128 + k * 2 + (mm & 1)]; }
            img[12 * 4096 + e] = (f16)v;
        }
    }
}

// ---------------- main fused kernel ----------------
__global__ __launch_bounds__(512, 2)
void gnn_mfma(const float* __restrict__ obs, const f16* __restrict__ img,
              const float* __restrict__ bp1, const float* __restrict__ b1,
              const float* __restrict__ bp2, const float* __restrict__ b2,
              const float* __restrict__ Mb1, const float* __restrict__ Mb2,
              const float* __restrict__ Mb3, const float* __restrict__ Mb4,
              float* __restrict__ out)
{
    // pure occupancy governor (no data LDS in this kernel at all)
    __shared__ __align__(16) float smem[LDS_PAD_F];
    const int tid  = threadIdx.x;
    if (tid == 0) { volatile float* g = smem; g[0] = 0.f; }

    const int w    = __builtin_amdgcn_readfirstlane(tid >> 6);
    const int l    = tid & 63;
    const int col  = l & 15;   // group within batch (D col / operand n)
    const int quad = l >> 4;   // feature sub-block (D row / operand k: quad*4+r)

    const int wid = blockIdx.x * NW + w;
    const int g0  = wid * 16;

    // per-lane obs base: group g0+col, feature offset quad*4
    const float* orow = obs + (size_t)(g0 + col) * 384 + quad * 4;

    // W^T A-frag (8 B/lane, 512 B/wave coalesced)
    auto loadW = [&](int baseH, int mt, int kt) -> half4_t {
        return *(const half4_t*)(img + baseH + (mt * 4 + kt) * 256 + l * 4);
    };
    // obs^T B-frag for (agent, kt): f32x4 -> f16x4
    auto loadObs = [&](const float* ob_, int a, int kt) -> half4_t {
        return cvt4(*(const float4_t*)(ob_ + a * 64 + kt * 16));
    };

    // ---- phase A: conv1 pool  n1 = max_a relu(Wp1^T obs_a^T + bp1) ----
    half4_t Wp1f[4][4];
    #pragma unroll
    for (int mt = 0; mt < 4; ++mt)
        #pragma unroll
        for (int kt = 0; kt < 4; ++kt) Wp1f[mt][kt] = loadW(0, mt, kt);
    float4_t bq[4];
    #pragma unroll
    for (int mt = 0; mt < 4; ++mt)
        bq[mt] = *(const float4_t*)(bp1 + mt * 16 + quad * 4);

    float4_t n1[4];
    #pragma unroll
    for (int mt = 0; mt < 4; ++mt) n1[mt] = bcast4(0.f);
    #pragma unroll
    for (int a = 0; a < 6; ++a) {
        half4_t ob[4];
        #pragma unroll
        for (int kt = 0; kt < 4; ++kt) ob[kt] = loadObs(orow, a, kt);
        #pragma unroll
        for (int mt = 0; mt < 4; ++mt) {
            float4_t acc = bq[mt];
            #pragma unroll
            for (int kt = 0; kt < 4; ++kt)
                acc = MFMA16(Wp1f[mt][kt], ob[kt], acc);
            n1[mt] = max4(n1[mt], acc);   // relu folded (init 0)
        }
    }

    // ---- c = Wn1^T n1^T + b1 (pure register chaining, no transpose!) ----
    half4_t n1h[4];
    #pragma unroll
    for (int kt = 0; kt < 4; ++kt) n1h[kt] = cvt4(n1[kt]);
    float4_t c[4];
    {
        int bW = 2 * 4096;
        asm volatile("" : "+s"(bW));   // stream, don't hoist earlier
        #pragma unroll
        for (int mt = 0; mt < 4; ++mt) {
            float4_t acc = *(const float4_t*)(b1 + mt * 16 + quad * 4);
            #pragma unroll
            for (int kt = 0; kt < 4; ++kt)
                acc = MFMA16(loadW(bW, mt, kt), n1h[kt], acc);
            c[mt] = acc;
        }
    }

    // ---- phase B: per agent h_a = tanh(Ws1^T obs_a^T + c); hbar += h_a;
    //      n2 = max_a relu(Wp2^T h_a^T + bp2) ----
    float4_t bp2q[4];
    #pragma unroll
    for (int mt = 0; mt < 4; ++mt)
        bp2q[mt] = *(const float4_t*)(bp2 + mt * 16 + quad * 4);
    // force obs re-load (don't keep phase-A values alive: 96 VGPRs)
    size_t orp = (size_t)orow;
    asm volatile("" : "+v"(orp));
    const float* orow2 = (const float*)orp;

    float4_t hbar[4], n2[4];
    #pragma unroll
    for (int mt = 0; mt < 4; ++mt) { hbar[mt] = bcast4(0.f); n2[mt] = bcast4(0.f); }
    #pragma unroll
    for (int a = 0; a < 6; ++a) {
        int bWs = 1 * 4096, bWp = 3 * 4096;
        asm volatile("" : "+s"(bWs), "+s"(bWp));  // per-agent streamed (L1-hot)
        half4_t ob[4];
        #pragma unroll
        for (int kt = 0; kt < 4; ++kt) ob[kt] = loadObs(orow2, a, kt);
        half4_t hh[4];
        #pragma unroll
        for (int mt = 0; mt < 4; ++mt) {
            float4_t acc = c[mt];
            #pragma unroll
            for (int kt = 0; kt < 4; ++kt)
                acc = MFMA16(loadW(bWs, mt, kt), ob[kt], acc);
            #pragma unroll
            for (int r = 0; r < 4; ++r) acc[r] = fast_tanh(acc[r]);
            hbar[mt] += acc;
            hh[mt] = cvt4(acc);
        }
        #pragma unroll
        for (int mt = 0; mt < 4; ++mt) {
            float4_t q = bp2q[mt];
            #pragma unroll
            for (int kt = 0; kt < 4; ++kt)
                q = MFMA16(loadW(bWp, mt, kt), hh[kt], q);
            n2[mt] = max4(n2[mt], q);
        }
    }
    #pragma unroll
    for (int mt = 0; mt < 4; ++mt) hbar[mt] *= (1.0f / 6.0f);

    // ---- res = Ws2^T hbar^T + Wn2^T n2^T + b2 ----
    half4_t hbh[4], n2h[4];
    #pragma unroll
    for (int kt = 0; kt < 4; ++kt) { hbh[kt] = cvt4(hbar[kt]); n2h[kt] = cvt4(n2[kt]); }
    float4_t rr[4];
    {
        int b4 = 4 * 4096, b5 = 5 * 4096;
        asm volatile("" : "+s"(b4), "+s"(b5));
        #pragma unroll
        for (int mt = 0; mt < 4; ++mt) {
            float4_t acc = *(const float4_t*)(b2 + mt * 16 + quad * 4);
            #pragma unroll
            for (int kt = 0; kt < 4; ++kt)
                acc = MFMA16(loadW(b4, mt, kt), hbh[kt], acc);
            #pragma unroll
            for (int kt = 0; kt < 4; ++kt)
                acc = MFMA16(loadW(b5, mt, kt), n2h[kt], acc);
            rr[mt] = acc;
        }
    }

    // ---- per-type 3-layer relu MLP, all register-chained ----
    half4_t x3h[2][4];
    #pragma unroll
    for (int ty = 0; ty < 2; ++ty) {
        half4_t xh[4];
        #pragma unroll
        for (int kt = 0; kt < 4; ++kt) xh[kt] = cvt4(rr[kt]);
        #pragma unroll
        for (int layer = 0; layer < 3; ++layer) {
            int bb = (6 + ty * 3 + layer) * 4096;
            asm volatile("" : "+s"(bb));          // streamed per layer
            const float* Mb = (layer == 0 ? Mb1 : layer == 1 ? Mb2 : Mb3) + ty * 64;
            float4_t nx[4];
            #pragma unroll
            for (int mt = 0; mt < 4; ++mt) {
                float4_t acc = *(const float4_t*)(Mb + mt * 16 + quad * 4);
                #pragma unroll
                for (int kt = 0; kt < 4; ++kt)
                    acc = MFMA16(loadW(bb, mt, kt), xh[kt], acc);
                nx[mt] = max4(acc, bcast4(0.f));  // relu
            }
            #pragma unroll
            for (int kt = 0; kt < 4; ++kt) xh[kt] = cvt4(nx[kt]);
        }
        #pragma unroll
        for (int kt = 0; kt < 4; ++kt) x3h[ty][kt] = xh[kt];
    }

    // ---- head: D rows 0..11 = 12 output slots, C-chained over both types ----
    float4_t d = bcast4(0.f);
    {
        int bh = 12 * 4096;
        asm volatile("" : "+s"(bh));
        #pragma unroll
        for (int kt = 0; kt < 4; ++kt)
            d = MFMA16(loadW(bh, 0, kt), x3h[0][kt], d);
        #pragma unroll
        for (int kt = 0; kt < 4; ++kt)
            d = MFMA16(loadW(bh + 1024, 0, kt), x3h[1][kt], d);
    }

    // store: lane(quad<3) holds rows quad*4..quad*4+3 for group g0+col ->
    // one coalesced float4 per lane at out[(g0+col)*12 + quad*4]
    if (quad < 3) {
        const float m00 = Mb4[0], m01 = Mb4[1], m10 = Mb4[2], m11 = Mb4[3];
        float4_t v;
        #pragma unroll
        for (int r = 0; r < 4; ++r) {
            const int slot = quad * 4 + r;
            const float mb = (slot < 10) ? ((r & 1) ? m01 : m00)
                                         : ((r & 1) ? m11 : m10);
            v[r] = fast_tanh(d[r] + mb);
        }
        *(float4_t*)(out + (size_t)(g0 + col) * 12 + quad * 4) = v;
    }
}

extern "C" void kernel_launch(void* const* d_in, const int* in_sizes, int n_in,
                              void* d_out, int out_size, void* d_ws, size_t ws_size,
                              hipStream_t stream)
{
    const float* obs = (const float*)d_in[0];
    const float* Wp1 = (const float*)d_in[1];
    const float* bp1 = (const float*)d_in[2];
    const float* Ws1 = (const float*)d_in[3];
    const float* Wn1 = (const float*)d_in[4];
    const float* b1  = (const float*)d_in[5];
    const float* Wp2 = (const float*)d_in[6];
    const float* bp2 = (const float*)d_in[7];
    const float* Ws2 = (const float*)d_in[8];
    const float* Wn2 = (const float*)d_in[9];
    const float* b2  = (const float*)d_in[10];
    const float* MW1 = (const float*)d_in[11];
    const float* Mb1 = (const float*)d_in[12];
    const float* MW2 = (const float*)d_in[13];
    const float* Mb2 = (const float*)d_in[14];
    const float* MW3 = (const float*)d_in[15];
    const float* Mb3 = (const float*)d_in[16];
    const float* MW4 = (const float*)d_in[17];
    const float* Mb4 = (const float*)d_in[18];
    float* out = (float*)d_out;
    f16* img = (f16*)d_ws;   // 12*4096 + 2048 = 51200 halfs = 100 KB

    hipLaunchKernelGGL(prep_weights, dim3(13), dim3(256), 0, stream,
                       Wp1, Ws1, Wn1, Wp2, Ws2, Wn2, MW1, MW2, MW3, MW4, img);
    // 1024 blocks x 8 waves x 16 groups = 131072
    hipLaunchKernelGGL(gnn_mfma, dim3(1024), dim3(512), 0, stream,
                       obs, img, bp1, b1, bp2, b2, Mb1, Mb2, Mb3, Mb4, out);
}

// Round 7
// 394.521 us; speedup vs baseline: 1.1929x; 1.1929x over previous
//
#include <hip/hip_runtime.h>
#include <math.h>

// GNNMLP via f16 MFMA, TRANSPOSED-ACTIVATION form. G=131072 groups x 6 agents.
// R6-verified algebra: for mfma_f32_16x16x16_f16, D layout (col=lane&15,
//   row=quad*4+reg) == operand layout (n=lane&15, k=quad*4+j), so a D-frag
//   cvt'd to f16 IS the next layer's B-operand. All layers computed transposed
//   (D = W^T x X^T, activations [feature][group], group-in-lane). Zero data
//   LDS, zero transposes, LDS bank conflicts = 0 (R6 counter-verified).
// ROUND-7 FIX (R6 post-mortem): R6 streamed every W-frag per-use behind
//   per-use opacity barriers -> allocator squeezed to 60 VGPR, ~360 serialized
//   load->waitcnt->MFMA round-trips/wave, 237 us. Now: per-PHASE W residency.
//   Each matmul phase loads its matrix ONCE into a reused W[4][2] half8 block
//   (8x dwordx4, issued together = one latency wait/phase, ~13 waits total),
//   opacity barrier at phase granularity only. Phase B split into two agent
//   loops (loop1: Ws1 resident, emits hh[6][4] f16; loop2: Wp2 resident, zero
//   loads). Obs: 1-deep raw-f32 prefetch in phase A (cold HBM), plain reload
//   in loop1 (L2-hot), "+v" barrier prevents cross-phase CSE of obs regs.
// OCCUPANCY (R1-R3 lesson): launch_bounds(512,2) + LDS pad 71680 B caps
//   2 blocks/CU = 4 waves/EU -> allocator targets 128 VGPR, no spill-squeeze.
// prep_weights: img = W^T A-frags, PAIRED packing: matrix m, pair (mt,kp):
//   img[m*4096 + (mt*2+kp)*512 + lane*8 + t], t=0..3 -> kt=2kp, t=4..7 ->
//   kt=2kp+1; element = W[k][n], k=kt*16+(lane>>4)*4+(t&3), n=mt*16+(lane&15).
//   Head: 2 ty sets a 12*4096 + ty*1024 + kp*512 (D rows 0..9 = ty0 slots,
//   10..11 = ty1, rest zero, C-chained over ty).
// Layouts (m89/m120-verified family, K=16 variant):
//   A[m][k]: m=lane&15, k=(lane>>4)*4+j   B[k][n]: n=lane&15, k=(lane>>4)*4+j
//   C/D:     col=lane&15, row=(lane>>4)*4+reg

typedef _Float16 f16;
typedef __fp16   fp16x2_t __attribute__((ext_vector_type(2)));
typedef _Float16 half4_t  __attribute__((ext_vector_type(4)));
typedef _Float16 half8_t  __attribute__((ext_vector_type(8)));
typedef float    float4_t __attribute__((ext_vector_type(4)));

#define NW 8            // waves per block
#define LDS_PAD_F 17920 // 71680 B: floor(163840/71680) = 2 blocks/CU cap

#define MFMA16(A,B,C) __builtin_amdgcn_mfma_f32_16x16x16f16((A),(B),(C),0,0,0)

__device__ __forceinline__ float fast_tanh(float x) {
    float e = __expf(2.0f * x);
    return 1.0f - 2.0f / (e + 1.0f);
}

__device__ __forceinline__ float4_t max4(float4_t a, float4_t b) {
    float4_t r;
    r[0] = fmaxf(a[0], b[0]); r[1] = fmaxf(a[1], b[1]);
    r[2] = fmaxf(a[2], b[2]); r[3] = fmaxf(a[3], b[3]);
    return r;
}

__device__ __forceinline__ float4_t bcast4(float v) {
    float4_t r; r[0] = v; r[1] = v; r[2] = v; r[3] = v; return r;
}

__device__ __forceinline__ half4_t flo(half8_t v) {
    half4_t r; r[0] = v[0]; r[1] = v[1]; r[2] = v[2]; r[3] = v[3]; return r;
}
__device__ __forceinline__ half4_t fhi(half8_t v) {
    half4_t r; r[0] = v[4]; r[1] = v[5]; r[2] = v[6]; r[3] = v[7]; return r;
}

// f32x4 -> f16x4 via 2 packed cvt
__device__ __forceinline__ half4_t cvt4(float4_t v) {
    fp16x2_t p0 = __builtin_amdgcn_cvt_pkrtz(v[0], v[1]);
    fp16x2_t p1 = __builtin_amdgcn_cvt_pkrtz(v[2], v[3]);
    half4_t r;
    r[0] = (f16)p0[0]; r[1] = (f16)p0[1]; r[2] = (f16)p1[0]; r[3] = (f16)p1[1];
    return r;
}

// ---------------- prep: W^T A-fragment image (paired packing) ----------------
__global__ void prep_weights(const float* __restrict__ Wp1, const float* __restrict__ Ws1,
                             const float* __restrict__ Wn1, const float* __restrict__ Wp2,
                             const float* __restrict__ Ws2, const float* __restrict__ Wn2,
                             const float* __restrict__ MW1, const float* __restrict__ MW2,
                             const float* __restrict__ MW3, const float* __restrict__ MW4,
                             f16* __restrict__ img)
{
    const int m = blockIdx.x;
    const int tid = threadIdx.x;
    if (m < 12) {
        const float* src;
        switch (m) {
            case 0: src = Wp1; break;  case 1: src = Ws1; break;
            case 2: src = Wn1; break;  case 3: src = Wp2; break;
            case 4: src = Ws2; break;  case 5: src = Wn2; break;
            case 6: src = MW1; break;  case 7: src = MW2; break;
            case 8: src = MW3; break;  case 9: src = MW1 + 4096; break;
            case 10: src = MW2 + 4096; break; default: src = MW3 + 4096; break;
        }
        for (int e = tid; e < 4096; e += 256) {
            const int p = e >> 9, mt = p >> 1, kp = p & 1;
            const int o = e & 511, lane = o >> 3, j8 = o & 7;
            const int kt = kp * 2 + (j8 >> 2), j = j8 & 3;
            const int k = kt * 16 + (lane >> 4) * 4 + j;
            const int n = mt * 16 + (lane & 15);
            img[m * 4096 + e] = (f16)src[k * 64 + n];
        }
    } else {
        for (int e = tid; e < 2048; e += 256) {
            const int ty = e >> 10, o = e & 1023;
            const int kp = o >> 9, oo = o & 511, lane = oo >> 3, j8 = oo & 7;
            const int kt = kp * 2 + (j8 >> 2), j = j8 & 3;
            const int k = kt * 16 + (lane >> 4) * 4 + j;
            const int mm = lane & 15;
            float v = 0.f;
            if (ty == 0) { if (mm < 10) v = MW4[k * 2 + (mm & 1)]; }
            else         { if (mm == 10 || mm == 11) v = MW4[128 + k * 2 + (mm & 1)]; }
            img[12 * 4096 + e] = (f16)v;
        }
    }
}

// ---------------- main fused kernel ----------------
__global__ __launch_bounds__(512, 2)
void gnn_mfma(const float* __restrict__ obs, const f16* __restrict__ img,
              const float* __restrict__ bp1, const float* __restrict__ b1,
              const float* __restrict__ bp2, const float* __restrict__ b2,
              const float* __restrict__ Mb1, const float* __restrict__ Mb2,
              const float* __restrict__ Mb3, const float* __restrict__ Mb4,
              float* __restrict__ out)
{
    // pure occupancy governor (no data LDS)
    __shared__ __align__(16) float smem[LDS_PAD_F];
    const int tid  = threadIdx.x;
    if (tid == 0) { volatile float* g = smem; g[0] = 0.f; }

    const int w    = __builtin_amdgcn_readfirstlane(tid >> 6);
    const int l    = tid & 63;
    const int col  = l & 15;   // group within batch (operand n / D col)
    const int quad = l >> 4;   // feature sub-block (operand k / D row: quad*4+r)

    const int wid = blockIdx.x * NW + w;
    const int g0  = wid * 16;
    const float* orow = obs + (size_t)(g0 + col) * 384 + quad * 4;

    // one matrix of W^T A-frags, reused across phases: W[mt][kp] = {kt=2kp, 2kp+1}
    half8_t W[4][2];
    auto loadWmat = [&](int baseH) {
        #pragma unroll
        for (int mt = 0; mt < 4; ++mt)
            #pragma unroll
            for (int kp = 0; kp < 2; ++kp)
                W[mt][kp] = *(const half8_t*)(img + baseH + (mt * 2 + kp) * 512 + l * 8);
    };
    auto wfrag = [&](int mt, int kt) -> half4_t {
        return (kt & 1) ? fhi(W[mt][kt >> 1]) : flo(W[mt][kt >> 1]);
    };

    // ---- phase A: conv1 pool  n1 = max_a relu(Wp1^T obs_a^T + bp1) ----
    loadWmat(0);
    float4_t bq[4];
    #pragma unroll
    for (int mt = 0; mt < 4; ++mt)
        bq[mt] = *(const float4_t*)(bp1 + mt * 16 + quad * 4);

    float4_t n1[4];
    #pragma unroll
    for (int mt = 0; mt < 4; ++mt) n1[mt] = bcast4(0.f);
    {
        // 1-deep raw-f32 obs prefetch (cold HBM)
        float4_t ox[4];
        #pragma unroll
        for (int kt = 0; kt < 4; ++kt)
            ox[kt] = *(const float4_t*)(orow + kt * 16);
        #pragma unroll
        for (int a = 0; a < 6; ++a) {
            half4_t ob[4];
            #pragma unroll
            for (int kt = 0; kt < 4; ++kt) ob[kt] = cvt4(ox[kt]);
            if (a < 5) {
                #pragma unroll
                for (int kt = 0; kt < 4; ++kt)
                    ox[kt] = *(const float4_t*)(orow + (a + 1) * 64 + kt * 16);
            }
            #pragma unroll
            for (int mt = 0; mt < 4; ++mt) {
                float4_t acc = bq[mt];
                #pragma unroll
                for (int kt = 0; kt < 4; ++kt)
                    acc = MFMA16(wfrag(mt, kt), ob[kt], acc);
                n1[mt] = max4(n1[mt], acc);   // relu folded (init 0)
            }
        }
    }

    // ---- c = Wn1^T n1^T + b1 (register chaining) ----
    half4_t n1h[4];
    #pragma unroll
    for (int kt = 0; kt < 4; ++kt) n1h[kt] = cvt4(n1[kt]);
    float4_t c[4];
    {
        int bW = 2 * 4096;
        asm volatile("" : "+s"(bW));   // phase-granular opacity
        loadWmat(bW);
        #pragma unroll
        for (int mt = 0; mt < 4; ++mt) {
            float4_t acc = *(const float4_t*)(b1 + mt * 16 + quad * 4);
            #pragma unroll
            for (int kt = 0; kt < 4; ++kt)
                acc = MFMA16(wfrag(mt, kt), n1h[kt], acc);
            c[mt] = acc;
        }
    }

    // ---- phase B loop1: h_a = tanh(Ws1^T obs_a^T + c); hbar += h_a; hh[a] kept ----
    size_t orp = (size_t)orow;
    asm volatile("" : "+v"(orp));      // no CSE with phase-A obs regs
    const float* orow2 = (const float*)orp;
    {
        int bWs = 1 * 4096;
        asm volatile("" : "+s"(bWs));
        loadWmat(bWs);
    }
    half4_t hh[6][4];
    float4_t hbar[4];
    #pragma unroll
    for (int mt = 0; mt < 4; ++mt) hbar[mt] = bcast4(0.f);
    #pragma unroll
    for (int a = 0; a < 6; ++a) {
        half4_t ob[4];
        #pragma unroll
        for (int kt = 0; kt < 4; ++kt)
            ob[kt] = cvt4(*(const float4_t*)(orow2 + a * 64 + kt * 16));  // L2-hot
        #pragma unroll
        for (int mt = 0; mt < 4; ++mt) {
            float4_t acc = c[mt];
            #pragma unroll
            for (int kt = 0; kt < 4; ++kt)
                acc = MFMA16(wfrag(mt, kt), ob[kt], acc);
            #pragma unroll
            for (int r = 0; r < 4; ++r) acc[r] = fast_tanh(acc[r]);
            hbar[mt] += acc;
            hh[a][mt] = cvt4(acc);
        }
    }

    // ---- phase B loop2: n2 = max_a relu(Wp2^T h_a^T + bp2) — zero loads inside ----
    float4_t n2[4];
    {
        int bWp = 3 * 4096;
        asm volatile("" : "+s"(bWp));
        loadWmat(bWp);
        float4_t bp2q[4];
        #pragma unroll
        for (int mt = 0; mt < 4; ++mt)
            bp2q[mt] = *(const float4_t*)(bp2 + mt * 16 + quad * 4);
        #pragma unroll
        for (int mt = 0; mt < 4; ++mt) n2[mt] = bcast4(0.f);
        #pragma unroll
        for (int a = 0; a < 6; ++a) {
            #pragma unroll
            for (int mt = 0; mt < 4; ++mt) {
                float4_t q = bp2q[mt];
                #pragma unroll
                for (int kt = 0; kt < 4; ++kt)
                    q = MFMA16(wfrag(mt, kt), hh[a][kt], q);
                n2[mt] = max4(n2[mt], q);
            }
        }
    }

    // ---- res = Ws2^T hbar^T + Wn2^T n2^T + b2 (two resident-W passes) ----
    half4_t hbh[4], n2h[4];
    #pragma unroll
    for (int kt = 0; kt < 4; ++kt) {
        hbh[kt] = cvt4(hbar[kt] * (1.0f / 6.0f));
        n2h[kt] = cvt4(n2[kt]);
    }
    float4_t rr[4];
    {
        int b4 = 4 * 4096;
        asm volatile("" : "+s"(b4));
        loadWmat(b4);
        #pragma unroll
        for (int mt = 0; mt < 4; ++mt) {
            float4_t acc = *(const float4_t*)(b2 + mt * 16 + quad * 4);
            #pragma unroll
            for (int kt = 0; kt < 4; ++kt)
                acc = MFMA16(wfrag(mt, kt), hbh[kt], acc);
            rr[mt] = acc;
        }
    }
    {
        int b5 = 5 * 4096;
        asm volatile("" : "+s"(b5));
        loadWmat(b5);
        #pragma unroll
        for (int mt = 0; mt < 4; ++mt) {
            #pragma unroll
            for (int kt = 0; kt < 4; ++kt)
                rr[mt] = MFMA16(wfrag(mt, kt), n2h[kt], rr[mt]);
        }
    }

    // ---- per-type 3-layer relu MLP, register-chained, W resident per layer ----
    half4_t x3h[2][4];
    #pragma unroll
    for (int ty = 0; ty < 2; ++ty) {
        half4_t xh[4];
        #pragma unroll
        for (int kt = 0; kt < 4; ++kt) xh[kt] = cvt4(rr[kt]);
        #pragma unroll
        for (int layer = 0; layer < 3; ++layer) {
            int bb = (6 + ty * 3 + layer) * 4096;
            asm volatile("" : "+s"(bb));
            loadWmat(bb);
            const float* Mb = (layer == 0 ? Mb1 : layer == 1 ? Mb2 : Mb3) + ty * 64;
            float4_t nx[4];
            #pragma unroll
            for (int mt = 0; mt < 4; ++mt) {
                float4_t acc = *(const float4_t*)(Mb + mt * 16 + quad * 4);
                #pragma unroll
                for (int kt = 0; kt < 4; ++kt)
                    acc = MFMA16(wfrag(mt, kt), xh[kt], acc);
                nx[mt] = max4(acc, bcast4(0.f));  // relu
            }
            #pragma unroll
            for (int kt = 0; kt < 4; ++kt) xh[kt] = cvt4(nx[kt]);
        }
        #pragma unroll
        for (int kt = 0; kt < 4; ++kt) x3h[ty][kt] = xh[kt];
    }

    // ---- head: D rows 0..11 = 12 output slots, C-chained over both types ----
    float4_t d = bcast4(0.f);
    {
        int bh = 12 * 4096;
        asm volatile("" : "+s"(bh));
        half8_t H0[2], H1[2];
        #pragma unroll
        for (int kp = 0; kp < 2; ++kp) {
            H0[kp] = *(const half8_t*)(img + bh + kp * 512 + l * 8);
            H1[kp] = *(const half8_t*)(img + bh + 1024 + kp * 512 + l * 8);
        }
        #pragma unroll
        for (int kt = 0; kt < 4; ++kt) {
            half4_t f = (kt & 1) ? fhi(H0[kt >> 1]) : flo(H0[kt >> 1]);
            d = MFMA16(f, x3h[0][kt], d);
        }
        #pragma unroll
        for (int kt = 0; kt < 4; ++kt) {
            half4_t f = (kt & 1) ? fhi(H1[kt >> 1]) : flo(H1[kt >> 1]);
            d = MFMA16(f, x3h[1][kt], d);
        }
    }

    // store: lane(quad<3) holds rows quad*4..+3 for group g0+col ->
    // one coalesced float4 per lane at out[(g0+col)*12 + quad*4]
    if (quad < 3) {
        const float m00 = Mb4[0], m01 = Mb4[1], m10 = Mb4[2], m11 = Mb4[3];
        float4_t v;
        #pragma unroll
        for (int r = 0; r < 4; ++r) {
            const int slot = quad * 4 + r;
            const float mb = (slot < 10) ? ((r & 1) ? m01 : m00)
                                         : ((r & 1) ? m11 : m10);
            v[r] = fast_tanh(d[r] + mb);
        }
        *(float4_t*)(out + (size_t)(g0 + col) * 12 + quad * 4) = v;
    }
}

extern "C" void kernel_launch(void* const* d_in, const int* in_sizes, int n_in,
                              void* d_out, int out_size, void* d_ws, size_t ws_size,
                              hipStream_t stream)
{
    const float* obs = (const float*)d_in[0];
    const float* Wp1 = (const float*)d_in[1];
    const float* bp1 = (const float*)d_in[2];
    const float* Ws1 = (const float*)d_in[3];
    const float* Wn1 = (const float*)d_in[4];
    const float* b1  = (const float*)d_in[5];
    const float* Wp2 = (const float*)d_in[6];
    const float* bp2 = (const float*)d_in[7];
    const float* Ws2 = (const float*)d_in[8];
    const float* Wn2 = (const float*)d_in[9];
    const float* b2  = (const float*)d_in[10];
    const float* MW1 = (const float*)d_in[11];
    const float* Mb1 = (const float*)d_in[12];
    const float* MW2 = (const float*)d_in[13];
    const float* Mb2 = (const float*)d_in[14];
    const float* MW3 = (const float*)d_in[15];
    const float* Mb3 = (const float*)d_in[16];
    const float* MW4 = (const float*)d_in[17];
    const float* Mb4 = (const float*)d_in[18];
    float* out = (float*)d_out;
    f16* img = (f16*)d_ws;   // 12*4096 + 2048 = 51200 halfs = 100 KB

    hipLaunchKernelGGL(prep_weights, dim3(13), dim3(256), 0, stream,
                       Wp1, Ws1, Wn1, Wp2, Ws2, Wn2, MW1, MW2, MW3, MW4, img);
    // 1024 blocks x 8 waves x 16 groups = 131072
    hipLaunchKernelGGL(gnn_mfma, dim3(1024), dim3(512), 0, stream,
                       obs, img, bp1, b1, bp2, b2, Mb1, Mb2, Mb3, Mb4, out);
}